// Round 9
// baseline (476.811 us; speedup 1.0000x reference)
//
#include <hip/hip_runtime.h>
#include <hip/hip_bf16.h>
#include <stdint.h>

typedef __attribute__((ext_vector_type(8))) short short8;   // 8 bf16 (4 VGPRs)
typedef __attribute__((ext_vector_type(4))) float f32x4;    // 4 fp32 acc
typedef __hip_bfloat16 bf16;

#define NB   8
#define LSEQ 2048
#define NM   256
#define DMODEL 1024
#define DO   256
#define BLR  16384   /* NB*LSEQ rows */
#define NCH  64      /* scan chunks (512 blocks -> 2 blocks/CU) */
#define CLK  32      /* chunk length */

__device__ __forceinline__ float sigm(float x) { return 1.f / (1.f + __expf(-x)); }

__device__ __forceinline__ void gl_lds16(const void* g, void* l) {
  __builtin_amdgcn_global_load_lds((const __attribute__((address_space(1))) void*)g,
                                   (__attribute__((address_space(3))) void*)l, 16, 0, 0);
}

// inline-asm LDS read: invisible to compiler alias analysis (no auto vmcnt(0)
// drain vs in-flight global_load_lds). Fenced by lgkmcnt(0)+sched_barrier(0).
__device__ __forceinline__ short8 ds_read128(const bf16* p) {
  short8 r;
  unsigned a = (unsigned)(uintptr_t)(const __attribute__((address_space(3))) bf16*)p;
  asm volatile("ds_read_b128 %0, %1" : "=v"(r) : "v"(a));
  return r;
}

__device__ __forceinline__ unsigned short bf16bits(float v) {
  bf16 b = __float2bfloat16(v);
  return *(unsigned short*)&b;
}
__device__ __forceinline__ float bits2f(unsigned short u) {
  bf16 b = *(bf16*)&u;
  return __bfloat162float(b);
}

// ---------------- prep: enc cvt + all weight cvts + e8l2a in ONE dispatch ------
// ranges: [0, 4194304) float4 enc cvt; then weight chains; then e8.

__global__ __launch_bounds__(256) void prep_kernel(
    const float* __restrict__ encoder_out, ushort4* __restrict__ encb4,
    const float* __restrict__ gate_w, const float* __restrict__ down_w,
    const float* __restrict__ up_w, const float* __restrict__ wr_w,
    const float* __restrict__ wi_w, const float* __restrict__ ow_w,
    const float* __restrict__ log_a,
    bf16* __restrict__ gate_wb, bf16* __restrict__ down_wb, bf16* __restrict__ up_wb,
    bf16* __restrict__ wrb, bf16* __restrict__ wib, bf16* __restrict__ owb,
    float* __restrict__ e8) {
  int i = blockIdx.x * 256 + threadIdx.x;
  if (i < 4194304) {
    float4 v = ((const float4*)encoder_out)[i];
    ushort4 o;
    o.x = bf16bits(v.x); o.y = bf16bits(v.y); o.z = bf16bits(v.z); o.w = bf16bits(v.w);
    encb4[i] = o;
    return;
  }
  i -= 4194304;
  if (i < 1048576) { gate_wb[i] = __float2bfloat16(gate_w[i]); return; }
  i -= 1048576;
  if (i < 262144) { down_wb[i] = __float2bfloat16(down_w[i]); return; }
  i -= 262144;
  if (i < 262144) { up_wb[i] = __float2bfloat16(up_w[i]); return; }
  i -= 262144;
  if (i < 196608) { wrb[i] = __float2bfloat16(wr_w[i]); return; }
  i -= 196608;
  if (i < 196608) { wib[i] = __float2bfloat16(wi_w[i]); return; }
  i -= 196608;
  if (i < 196608) { owb[i] = __float2bfloat16(ow_w[i]); return; }
  i -= 196608;
  if (i < 768) {
    float ab = 1.f / (1.f + expf(-log_a[i]));
    e8[i] = 8.f * log2f(ab);
  }
}

// ---------------- EMA + bucket, merged (blocks 0..31 ema, 32..95 bucket) -------

__global__ __launch_bounds__(256) void ema_bucket_kernel(const float* __restrict__ cpt,
                                                         const float* __restrict__ bprobs,
                                                         const int* __restrict__ bidx,
                                                         float* __restrict__ smoothed,
                                                         int* __restrict__ bucket) {
  if (blockIdx.x < NB * 4) {
    int b = blockIdx.x >> 2;
    int c = ((blockIdx.x & 3) << 8) + threadIdx.x;
    __shared__ float p[NM];
    p[threadIdx.x] = bprobs[b * LSEQ + bidx[b * NM + threadIdx.x]];
    __syncthreads();
    const float* cp = cpt + (size_t)b * NM * DMODEL + c;
    float* sp = smoothed + (size_t)b * NM * DMODEL + c;
    float h = 0.f;
    for (int m = 0; m < NM; ++m) {
      float pm = p[m];
      h = pm * cp[(size_t)m * DMODEL] + (1.f - pm) * h;
      sp[(size_t)m * DMODEL] = h;
    }
  } else {
    int i = (blockIdx.x - NB * 4) * 256 + threadIdx.x;
    int b = i >> 11, l = i & 2047;
    const int* bi = bidx + b * NM;
    int lo = 0, hi = NM;
    while (lo < hi) {
      int mid = (lo + hi) >> 1;
      if (bi[mid] <= l) lo = mid + 1; else hi = mid;
    }
    int v = lo - 1;
    bucket[i] = v < 0 ? 0 : v;
  }
}

// ---------------- gate + plugback elementwise (split from G1 epilogue) ----------
// h0 holds raw gemm logits (bf16); transformed IN PLACE:
// h0[m][n] = (1-p[m]) * sigm(h0[m][n] + gb[n]) * enc[m][n] + smoothed[b][bucket[m]][n]

__global__ __launch_bounds__(256) void gate_plug_kernel(bf16* __restrict__ h0,
                                                        const bf16* __restrict__ encb,
                                                        const float* __restrict__ gbias,
                                                        const float* __restrict__ bprobs,
                                                        const int* __restrict__ bucket,
                                                        const float* __restrict__ smoothed) {
  const int m = blockIdx.x;
  const int t = threadIdx.x;
  const int b = m >> 11;
  const float pm1 = 1.f - bprobs[m];
  const float* srow = smoothed + ((size_t)(b * NM + bucket[m])) * DMODEL + t * 4;
  const size_t base = (size_t)m * DMODEL + t * 4;
  ushort4 gr = *(const ushort4*)(h0 + base);
  ushort4 er = *(const ushort4*)(encb + base);
  float4 sm4 = *(const float4*)srow;
  float4 gb4 = *(const float4*)(gbias + t * 4);
  ushort4 o;
  o.x = bf16bits(pm1 * sigm(bits2f(gr.x) + gb4.x) * bits2f(er.x) + sm4.x);
  o.y = bf16bits(pm1 * sigm(bits2f(gr.y) + gb4.y) * bits2f(er.y) + sm4.y);
  o.z = bf16bits(pm1 * sigm(bits2f(gr.z) + gb4.z) * bits2f(er.z) + sm4.z);
  o.w = bf16bits(pm1 * sigm(bits2f(gr.w) + gb4.w) * bits2f(er.w) + sm4.w);
  *(ushort4*)(h0 + base) = o;
}

// ---------------- depthwise causal conv k=4, vectorized ushort4 ----------------
// thread handles 4 consecutive channels of one (b,l) row. grid = BLR*64/256.

__global__ __launch_bounds__(256) void conv_kernel(const bf16* __restrict__ x,
                                                   const float* __restrict__ cw,
                                                   const float* __restrict__ cb,
                                                   bf16* __restrict__ xcb) {
  int i4 = blockIdx.x * 256 + threadIdx.x;   // 4-channel group index
  int cg = i4 & 63;
  int bl = i4 >> 6;
  int l = bl & 2047;
  int c0 = cg << 2;
  float wf[4][4];
#pragma unroll
  for (int cc = 0; cc < 4; ++cc) {
    float4 w4 = ((const float4*)cw)[c0 + cc];
    wf[cc][0] = w4.x; wf[cc][1] = w4.y; wf[cc][2] = w4.z; wf[cc][3] = w4.w;
  }
  float4 cb4 = *(const float4*)(cb + c0);
  float s0 = cb4.x, s1 = cb4.y, s2 = cb4.z, s3 = cb4.w;
#pragma unroll
  for (int kk = 0; kk < 4; ++kk) {
    int ll = l - 3 + kk;
    if (ll >= 0) {
      ushort4 xv = *(const ushort4*)(x + (size_t)(bl + kk - 3) * DO + c0);
      s0 += wf[0][kk] * bits2f(xv.x);
      s1 += wf[1][kk] * bits2f(xv.y);
      s2 += wf[2][kk] * bits2f(xv.z);
      s3 += wf[3][kk] * bits2f(xv.w);
    }
  }
  ushort4 o;
  o.x = bf16bits(s0); o.y = bf16bits(s1); o.z = bf16bits(s2); o.w = bf16bits(s3);
  *(ushort4*)(xcb + (size_t)bl * DO + c0) = o;
}

// ---------------- chunked scan, 2 dispatches, 512 blocks each ----------------
// input packed uint: lo16 = d = 1-a (bf16), hi16 = s (bf16). h = (1-d)*h + s.

__global__ __launch_bounds__(256) void scan_p1(const unsigned int* __restrict__ ds,
                                               float2* __restrict__ AS) {
  int b = blockIdx.x / NCH, ch = blockIdx.x % NCH, c = threadIdx.x;
  size_t base = ((size_t)b * LSEQ + ch * CLK) * DO + c;
  float A = 1.f, S = 0.f;
  for (int t = 0; t < CLK; ++t) {
    unsigned int u = ds[base + (size_t)t * DO];
    float d = bits2f((unsigned short)(u & 0xffff));
    float s = bits2f((unsigned short)(u >> 16));
    float a = 1.f - d;
    A *= a;
    S = __builtin_fmaf(a, S, s);
  }
  AS[blockIdx.x * DO + c] = make_float2(A, S);
}

__global__ __launch_bounds__(256) void scan_p2(const unsigned int* __restrict__ ds,
                                               const float2* __restrict__ AS,
                                               bf16* __restrict__ hs) {
  int b = blockIdx.x / NCH, ch = blockIdx.x % NCH, c = threadIdx.x;
  // prefix over earlier chunks of this batch (L2-hot, <NCH iterations)
  float h = 0.f;
  for (int j = 0; j < ch; ++j) {
    float2 as = AS[(b * NCH + j) * DO + c];
    h = __builtin_fmaf(as.x, h, as.y);
  }
  size_t base = ((size_t)b * LSEQ + ch * CLK) * DO + c;
  for (int t = 0; t < CLK; ++t) {
    unsigned int u = ds[base + (size_t)t * DO];
    float d = bits2f((unsigned short)(u & 0xffff));
    float s = bits2f((unsigned short)(u >> 16));
    h = __builtin_fmaf(-d, h, h) + s;   // (1-d)*h + s
    hs[base + (size_t)t * DO] = __float2bfloat16(h);
  }
}

// ---------------- final rmsnorm over 1024, bf16 in -> f32 out ----------------

__global__ __launch_bounds__(256) void rmsnorm1024_kernel(const bf16* __restrict__ in,
                                                          const float* __restrict__ w,
                                                          float* __restrict__ out) {
  int row = blockIdx.x, t = threadIdx.x;
  ushort4 raw = ((const ushort4*)(in + (size_t)row * 1024))[t];
  float v0 = bits2f(raw.x), v1 = bits2f(raw.y), v2 = bits2f(raw.z), v3 = bits2f(raw.w);
  float ss = v0 * v0 + v1 * v1 + v2 * v2 + v3 * v3;
#pragma unroll
  for (int ofs = 32; ofs > 0; ofs >>= 1) ss += __shfl_down(ss, ofs, 64);
  __shared__ float wsum[4];
  if ((t & 63) == 0) wsum[t >> 6] = ss;
  __syncthreads();
  float tot = wsum[0] + wsum[1] + wsum[2] + wsum[3];
  float sc = rsqrtf(tot * (1.f / 1024.f) + 1e-6f);
  float4 wv = ((const float4*)w)[t];
  float4 o;
  o.x = v0 * sc * wv.x; o.y = v1 * sc * wv.y;
  o.z = v2 * sc * wv.z; o.w = v3 * sc * wv.w;
  ((float4*)(out + (size_t)row * 1024))[t] = o;
}

// ---------------- generic 64x128-tile 2-phase GEMM, occupancy-first ----------
// Used for down-proj (NC=256, KC=1024, grid 256x2) and up-proj (NC=1024,
// KC=256, grid 256x8 = 2048 blocks). LDS 24KB, acc 32 VGPR -> 4 blocks/CU.

template <int NC, int KC>
__global__ __launch_bounds__(256, 4) void gemm_t64(const bf16* __restrict__ A,
                                                   const bf16* __restrict__ W,
                                                   bf16* __restrict__ outb) {
  __shared__ __align__(16) bf16 As[64 * 64];    //  8 KB
  __shared__ __align__(16) bf16 Bs[128 * 64];   // 16 KB
  const int t = threadIdx.x;
  const int lane = t & 63;
  const int wv = t >> 6;
  const int wm = wv >> 1, wn = wv & 1;   // 2x2 waves, wave tile 32x64
  const int quad = lane >> 4, l16 = lane & 15;
  const int bm = blockIdx.x << 6, bn = blockIdx.y << 7;

  f32x4 acc[2][4] = {};

  for (int k0 = 0; k0 < KC; k0 += 64) {
    __syncthreads();
#pragma unroll
    for (int i = 0; i < 2; ++i) {   // A: 64 rows x 64 k
      int slot = i * 256 + t;
      int m = slot >> 3, lk8 = (slot & 7) ^ (m & 7);
      gl_lds16(A + (size_t)(bm + m) * KC + k0 + lk8 * 8, As + slot * 8);
    }
#pragma unroll
    for (int i = 0; i < 4; ++i) {   // B: 128 rows x 64 k
      int slot = i * 256 + t;
      int n = slot >> 3, lk8 = (slot & 7) ^ (n & 7);
      gl_lds16(W + (size_t)(bn + n) * KC + k0 + lk8 * 8, Bs + slot * 8);
    }
    __syncthreads();
#pragma unroll
    for (int ks = 0; ks < 2; ++ks) {
      short8 af[2], bfr[4];
#pragma unroll
      for (int i = 0; i < 2; ++i) {
        int m = wm * 32 + i * 16 + l16;
        int pa = (ks * 4 + quad) ^ (m & 7);
        af[i] = *(const short8*)(As + m * 64 + pa * 8);
      }
#pragma unroll
      for (int j = 0; j < 4; ++j) {
        int n = wn * 64 + j * 16 + l16;
        int pb = (ks * 4 + quad) ^ (n & 7);
        bfr[j] = *(const short8*)(Bs + n * 64 + pb * 8);
      }
#pragma unroll
      for (int i = 0; i < 2; ++i)
#pragma unroll
        for (int j = 0; j < 4; ++j)
          acc[i][j] = __builtin_amdgcn_mfma_f32_16x16x32_bf16(af[i], bfr[j], acc[i][j], 0, 0, 0);
    }
  }

#pragma unroll
  for (int i = 0; i < 2; ++i)
#pragma unroll
    for (int j = 0; j < 4; ++j)
#pragma unroll
      for (int r = 0; r < 4; ++r) {
        int m = bm + wm * 32 + i * 16 + quad * 4 + r;
        int n = bn + wn * 64 + j * 16 + l16;
        outb[(size_t)m * NC + n] = __float2bfloat16(acc[i][j][r]);
      }
}

// ---------------- 256x256 8-phase GEMM (T2+T3+T4+T5), N = DMODEL, pure ----------
// Used for G1 only (K=1024: 8 full pipeline iterations).

template <int KC>
__global__ __launch_bounds__(512, 2) void gemm256(const bf16* __restrict__ Ag,
                                                  const bf16* __restrict__ W,
                                                  bf16* __restrict__ outb) {
  __shared__ __align__(16) bf16 lds[2][4][128 * 64];   // [buf][A0,A1,B0,B1][...]
  const int t = threadIdx.x;
  const int lane = t & 63;
  const int wv = t >> 6;
  const int wm = wv >> 2, wn = wv & 3;
  const int quad = lane >> 4, l16 = lane & 15;
  const int bm = blockIdx.x << 8, bn = blockIdx.y << 8;
  constexpr int KT = KC >> 6;   // # 64-wide k-tiles (power of 2, >= 4)
  constexpr int KM = KT - 1;

  const int rr = t >> 3;                 // 0..63 staging row (q=0); q=1 adds +128 global
  const int cc = (t & 7) ^ (rr & 7);     // pre-swizzled source chunk

  f32x4 acc[8][4] = {};
  short8 af[4][2], bfr[2][2];

#define STAGE_A(BUF, H, KTI)                                                      \
  {                                                                               \
    int kk = ((KTI) & KM) << 6;                                                   \
    const bf16* s0 = Ag + (size_t)(bm + (H) * 64 + rr) * KC + kk + cc * 8;        \
    gl_lds16(s0, &lds[BUF][H][t * 8]);                                            \
    const bf16* s1 = Ag + (size_t)(bm + (H) * 64 + rr + 128) * KC + kk + cc * 8;  \
    gl_lds16(s1, &lds[BUF][H][(512 + t) * 8]);                                    \
  }
#define STAGE_B(BUF, H, KTI)                                                      \
  {                                                                               \
    int kk = ((KTI) & KM) << 6;                                                   \
    int n0 = (H) * 32 + (rr & 31) + ((rr >> 5) << 6);                             \
    const bf16* s0 = W + (size_t)(bn + n0) * KC + kk + cc * 8;                    \
    gl_lds16(s0, &lds[BUF][2 + (H)][t * 8]);                                      \
    const bf16* s1 = W + (size_t)(bn + n0 + 128) * KC + kk + cc * 8;              \
    gl_lds16(s1, &lds[BUF][2 + (H)][(512 + t) * 8]);                              \
  }
#define LD_A(BUF, MG)                                                             \
  _Pragma("unroll") for (int ii = 0; ii < 4; ++ii) {                              \
    int r = wm * 64 + ii * 16 + l16;                                              \
    _Pragma("unroll") for (int ks = 0; ks < 2; ++ks) {                            \
      int ch = (ks * 4 + quad) ^ (r & 7);                                         \
      af[ii][ks] = ds_read128(&lds[BUF][MG][(r * 8 + ch) * 8]);                   \
    }                                                                             \
  }
#define LD_B(BUF, NG)                                                             \
  _Pragma("unroll") for (int jj = 0; jj < 2; ++jj) {                              \
    int r = wn * 32 + jj * 16 + l16;                                              \
    _Pragma("unroll") for (int ks = 0; ks < 2; ++ks) {                            \
      int ch = (ks * 4 + quad) ^ (r & 7);                                         \
      bfr[jj][ks] = ds_read128(&lds[BUF][2 + (NG)][(r * 8 + ch) * 8]);            \
    }                                                                             \
  }
#define MMA(MG, NG)                                                               \
  _Pragma("unroll") for (int ks = 0; ks < 2; ++ks)                                \
  _Pragma("unroll") for (int ii = 0; ii < 4; ++ii)                                \
  _Pragma("unroll") for (int jj = 0; jj < 2; ++jj)                                \
    acc[(MG) * 4 + ii][(NG) * 2 + jj] = __builtin_amdgcn_mfma_f32_16x16x32_bf16(  \
        af[ii][ks], bfr[jj][ks], acc[(MG) * 4 + ii][(NG) * 2 + jj], 0, 0, 0);
#define BARR __builtin_amdgcn_s_barrier()
#define WAIT_LGKM asm volatile("s_waitcnt lgkmcnt(0)" ::: "memory")
#define WAIT_VM6 asm volatile("s_waitcnt vmcnt(6)" ::: "memory")
#define SBAR __builtin_amdgcn_sched_barrier(0)
#define PH(MG, NG)                   \
  BARR; WAIT_LGKM; SBAR;             \
  __builtin_amdgcn_s_setprio(1);     \
  MMA(MG, NG);                       \
  __builtin_amdgcn_s_setprio(0);     \
  SBAR;                              \
  BARR;
#define PH_V(MG, NG)                 \
  BARR; WAIT_LGKM; SBAR;             \
  __builtin_amdgcn_s_setprio(1);     \
  MMA(MG, NG);                       \
  __builtin_amdgcn_s_setprio(0);     \
  SBAR;                              \
  WAIT_VM6;                          \
  BARR;

  // prologue: buf0 <- kt0 complete; buf1 <- kt1 {A0, A1, B1} (B0 staged at g1)
  STAGE_A(0, 0, 0) STAGE_A(0, 1, 0) STAGE_B(0, 0, 0) STAGE_B(0, 1, 0)
  STAGE_A(1, 0, 1) STAGE_A(1, 1, 1) STAGE_B(1, 1, 1)
  WAIT_VM6;   // buf0's 8 loads (oldest) complete; buf1's 6 stay in flight
  BARR;

#pragma unroll 1
  for (int it = 0; it < (KT >> 1); ++it) {
    const int kt = it * 2;
    LD_A(0, 0) LD_B(0, 0)
    STAGE_B(1, 0, kt + 1)
    PH(0, 0)
    LD_B(0, 1)
    STAGE_A(0, 0, kt + 2)
    PH(0, 1)
    LD_A(0, 1)
    STAGE_B(0, 1, kt + 2)
    PH(1, 1)
    LD_B(0, 0)
    STAGE_A(0, 1, kt + 2)
    PH_V(1, 0)
    LD_A(1, 0) LD_B(1, 0)
    STAGE_B(0, 0, kt + 2)
    PH(0, 0)
    LD_B(1, 1)
    STAGE_A(1, 0, kt + 3)
    PH(0, 1)
    LD_A(1, 1)
    STAGE_B(1, 1, kt + 3)
    PH(1, 1)
    LD_B(1, 0)
    STAGE_A(1, 1, kt + 3)
    PH_V(1, 0)
  }

#undef STAGE_A
#undef STAGE_B
#undef LD_A
#undef LD_B
#undef MMA
#undef BARR
#undef WAIT_LGKM
#undef WAIT_VM6
#undef SBAR
#undef PH
#undef PH_V

#pragma unroll
  for (int i = 0; i < 8; ++i) {
#pragma unroll
    for (int j = 0; j < 4; ++j) {
#pragma unroll
      for (int r = 0; r < 4; ++r) {
        int m = bm + wm * 128 + i * 16 + quad * 4 + r;
        int n = bn + wn * 64 + j * 16 + l16;
        outb[(size_t)m * DMODEL + n] = __float2bfloat16(acc[i][j][r]);
      }
    }
  }
}

// ---------------- dual GEMM v2: occupancy-tiled 32x128, 1024 blocks ----------------

__global__ __launch_bounds__(256, 4) void gemm_ri(const bf16* __restrict__ A,
                                                  const bf16* __restrict__ Wr,
                                                  const bf16* __restrict__ Wi,
                                                  const float* __restrict__ rbias,
                                                  const float* __restrict__ ibias,
                                                  const float* __restrict__ e8,
                                                  unsigned int* __restrict__ ds_out) {
  __shared__ __align__(16) bf16 As[32 * 64];    //  4 KB
  __shared__ __align__(16) bf16 Br[128 * 64];   // 16 KB
  __shared__ __align__(16) bf16 Bi[128 * 64];   // 16 KB
  const int t = threadIdx.x;
  const int lane = t & 63;
  const int wv = t >> 6;
  const int wm = wv >> 1, wn = wv & 1;    // 2x2 waves, wave tile 16x64
  const int quad = lane >> 4, l16 = lane & 15;
  const int bm = blockIdx.x << 5;         // 32-row tile
  const int bn = blockIdx.y << 7;         // 128-col tile

  f32x4 ar[4] = {};
  f32x4 ai[4] = {};

  for (int k0 = 0; k0 < DO; k0 += 64) {
    __syncthreads();
    {  // A: 32 rows x 64 k, one 16B chunk per thread
      int m = t >> 3, lk8 = (t & 7) ^ (m & 7);
      gl_lds16(A + (size_t)(bm + m) * DO + k0 + lk8 * 8, As + t * 8);
    }
#pragma unroll
    for (int i = 0; i < 4; ++i) {  // Wr/Wi: 128 rows x 64 k each
      int slot = i * 256 + t;
      int n = slot >> 3, lk8 = (slot & 7) ^ (n & 7);
      gl_lds16(Wr + (size_t)(bn + n) * DO + k0 + lk8 * 8, Br + slot * 8);
      gl_lds16(Wi + (size_t)(bn + n) * DO + k0 + lk8 * 8, Bi + slot * 8);
    }
    __syncthreads();
#pragma unroll
    for (int ks = 0; ks < 2; ++ks) {
      int m = wm * 16 + l16;
      int pa = (ks * 4 + quad) ^ (m & 7);
      short8 af = *(const short8*)(As + m * 64 + pa * 8);
#pragma unroll
      for (int j = 0; j < 4; ++j) {
        int n = wn * 64 + j * 16 + l16;
        int pb = (ks * 4 + quad) ^ (n & 7);
        short8 br = *(const short8*)(Br + n * 64 + pb * 8);
        short8 bi = *(const short8*)(Bi + n * 64 + pb * 8);
        ar[j] = __builtin_amdgcn_mfma_f32_16x16x32_bf16(af, br, ar[j], 0, 0, 0);
        ai[j] = __builtin_amdgcn_mfma_f32_16x16x32_bf16(af, bi, ai[j], 0, 0, 0);
      }
    }
  }

#pragma unroll
  for (int j = 0; j < 4; ++j) {
    int n = bn + wn * 64 + j * 16 + l16;
    float rb = rbias[n], ib = ibias[n], e8n = e8[n];
#pragma unroll
    for (int r = 0; r < 4; ++r) {
      int m = bm + wm * 16 + quad * 4 + r;
      size_t idx = (size_t)m * DO + n;
      float rv = sigm(ar[j][r] + rb);
      float a = exp2f(rv * e8n);
      float d = 1.f - a;                               // ~5e-3, bf16-safe
      float iv = sigm(ai[j][r] + ib);
      float xc = __bfloat162float(A[idx]);             // xconv[m][n] == A[m][n]
      float s = sqrtf(fmaxf(1.f - a * a, 0.f)) * iv * xc;
      ds_out[idx] = (unsigned int)bf16bits(d) | ((unsigned int)bf16bits(s) << 16);
    }
  }
}

// ---------------- out-proj GEMM v2: 32x256 tiles + fused RMSNorm(256) -----------
// grid BLR/32 = 512 blocks, acc 32 VGPR, LDS 36.5KB.

__global__ __launch_bounds__(256, 4) void gemm_on(const bf16* __restrict__ A,   // hs [BLR,256]
                                                  const bf16* __restrict__ W,   // ow [256,256]
                                                  const float* __restrict__ rnw,
                                                  bf16* __restrict__ xb) {
  __shared__ __align__(16) bf16 As[32 * 64];    //  4 KB
  __shared__ __align__(16) bf16 Bs[256 * 64];   // 32 KB
  __shared__ float red[4][32];
  const int t = threadIdx.x;
  const int lane = t & 63;
  const int wn = t >> 6;           // wave = column slice of 64
  const int quad = lane >> 4, l16 = lane & 15;
  const int bm = blockIdx.x << 5;  // 32-row tile

  f32x4 acc[2][4] = {};

  for (int k0 = 0; k0 < DO; k0 += 64) {
    __syncthreads();
    {  // A: 32 rows x 64 k, one chunk per thread
      int m = t >> 3, lk8 = (t & 7) ^ (m & 7);
      gl_lds16(A + (size_t)(bm + m) * DO + k0 + lk8 * 8, As + t * 8);
    }
#pragma unroll
    for (int i = 0; i < 8; ++i) {  // B: 256 rows x 64 k
      int slot = i * 256 + t;
      int n = slot >> 3, lk8 = (slot & 7) ^ (n & 7);
      gl_lds16(W + (size_t)n * DO + k0 + lk8 * 8, Bs + slot * 8);
    }
    __syncthreads();
#pragma unroll
    for (int ks = 0; ks < 2; ++ks) {
      short8 af[2], bfr[4];
#pragma unroll
      for (int i = 0; i < 2; ++i) {
        int m = i * 16 + l16;
        int pa = (ks * 4 + quad) ^ (m & 7);
        af[i] = *(const short8*)(As + m * 64 + pa * 8);
      }
#pragma unroll
      for (int j = 0; j < 4; ++j) {
        int n = wn * 64 + j * 16 + l16;
        int pb = (ks * 4 + quad) ^ (n & 7);
        bfr[j] = *(const short8*)(Bs + n * 64 + pb * 8);
      }
#pragma unroll
      for (int i = 0; i < 2; ++i)
#pragma unroll
        for (int j = 0; j < 4; ++j)
          acc[i][j] = __builtin_amdgcn_mfma_f32_16x16x32_bf16(af[i], bfr[j], acc[i][j], 0, 0, 0);
    }
  }

  float part[2][4];
#pragma unroll
  for (int i = 0; i < 2; ++i)
#pragma unroll
    for (int r = 0; r < 4; ++r) {
      float s = 0.f;
#pragma unroll
      for (int j = 0; j < 4; ++j) s += acc[i][j][r] * acc[i][j][r];
      part[i][r] = s;
    }
#pragma unroll
  for (int mask = 1; mask <= 8; mask <<= 1)
#pragma unroll
    for (int i = 0; i < 2; ++i)
#pragma unroll
      for (int r = 0; r < 4; ++r) part[i][r] += __shfl_xor(part[i][r], mask, 64);
  if (l16 == 0) {
#pragma unroll
    for (int i = 0; i < 2; ++i)
#pragma unroll
      for (int r = 0; r < 4; ++r) red[wn][i * 16 + quad * 4 + r] = part[i][r];
  }
  __syncthreads();
#pragma unroll
  for (int i = 0; i < 2; ++i) {
#pragma unroll
    for (int r = 0; r < 4; ++r) {
      int ml = i * 16 + quad * 4 + r;
      float tot = red[0][ml] + red[1][ml] + red[2][ml] + red[3][ml];
      float sc = rsqrtf(tot * (1.f / 256.f) + 1e-6f);
#pragma unroll
      for (int j = 0; j < 4; ++j) {
        int n = wn * 64 + j * 16 + l16;
        xb[(size_t)(bm + ml) * DO + n] = __float2bfloat16(acc[i][j][r] * sc * rnw[n]);
      }
    }
  }
}

// ---------------- launch ----------------

extern "C" void kernel_launch(void* const* d_in, const int* in_sizes, int n_in,
                              void* d_out, int out_size, void* d_ws, size_t ws_size,
                              hipStream_t stream) {
  const float* concept_out = (const float*)d_in[0];
  const float* encoder_out = (const float*)d_in[1];
  const float* bprobs      = (const float*)d_in[2];
  const int*   bidx        = (const int*)d_in[3];
  const float* gate_w      = (const float*)d_in[4];
  const float* gate_b      = (const float*)d_in[5];
  const float* down_w      = (const float*)d_in[6];
  const float* up_w        = (const float*)d_in[7];
  const float* norm_out_w  = (const float*)d_in[8];
  const float* rc_w        = (const float*)d_in[9];
  const float* rc_b        = (const float*)d_in[10];
  const float* wr_w        = (const float*)d_in[11];
  const float* wr_b        = (const float*)d_in[12];
  const float* wi_w        = (const float*)d_in[13];
  const float* wi_b        = (const float*)d_in[14];
  const float* log_a       = (const float*)d_in[15];
  const float* ow_w        = (const float*)d_in[16];
  const float* rn_w        = (const float*)d_in[17];
  float* out = (float*)d_out;
  (void)in_sizes; (void)n_in; (void)out_size; (void)ws_size;

  char* base = (char*)d_ws;
  size_t off = 0;
  auto alloc = [&](size_t bytes) -> char* {
    char* p = base + off;
    off += (bytes + 255) & ~(size_t)255;
    return p;
  };
  float* smoothed = (float*)alloc((size_t)NB * NM * DMODEL * 4);   // 8 MB
  int*   bucket   = (int*)alloc((size_t)BLR * 4);
  bf16*  gate_wb  = (bf16*)alloc((size_t)DMODEL * DMODEL * 2);
  bf16*  down_wb  = (bf16*)alloc((size_t)DO * DMODEL * 2);
  bf16*  up_wb    = (bf16*)alloc((size_t)DMODEL * DO * 2);
  bf16*  wrb      = (bf16*)alloc((size_t)3 * DO * DO * 2);
  bf16*  wib      = (bf16*)alloc((size_t)3 * DO * DO * 2);
  bf16*  owb      = (bf16*)alloc((size_t)3 * DO * DO * 2);
  float* e8       = (float*)alloc(3 * DO * 4);
  float2* ASsum   = (float2*)alloc((size_t)NB * NCH * DO * 8);     // 1 MB chunk summaries
  bf16*  xb       = (bf16*)alloc((size_t)BLR * DO * 2);            // 8 MB layer io

  // reused overlay region — offsets computed from actual buffer sizes
  const size_t SZ_ENC   = (size_t)BLR * DMODEL * 2;   // 32 MB
  const size_t SZ_XCONV = (size_t)BLR * DO * 2;       //  8 MB
  const size_t SZ_DS    = (size_t)BLR * DO * 4;       // 16 MB (packed uint32!)
  char* RA = alloc(2 * SZ_ENC);                       // 64 MB
  // head overlays
  bf16*  encb = (bf16*)RA;
  bf16*  h0b  = (bf16*)(RA + SZ_ENC);   // raw G1 logits, then gated in-place
  // layer overlays (xconvb | dsbuf | hsb disjoint: 8 + 16 + 8 = 32 MB)
  bf16*         xconvb = (bf16*)RA;
  unsigned int* dsbuf  = (unsigned int*)(RA + SZ_XCONV);
  bf16*         hsb    = (bf16*)(RA + SZ_XCONV + SZ_DS);
  // tail overlay
  bf16*  tmp2b  = (bf16*)RA;

  // prep: enc cvt (4194304 vec4) + weight cvts (2162688) + e8 (768)
  prep_kernel<<<(4194304 + 2163456 + 255) / 256, 256, 0, stream>>>(
      encoder_out, (ushort4*)encb,
      gate_w, down_w, up_w, wr_w, wi_w, ow_w, log_a,
      gate_wb, down_wb, up_wb, wrb, wib, owb, e8);
  ema_bucket_kernel<<<NB * 4 + BLR / 256, 256, 0, stream>>>(
      concept_out, bprobs, bidx, smoothed, bucket);

  // G1: pure gate GEMM -> h0b (raw logits), then fused gate+plugback in place
  gemm256<DMODEL><<<dim3(BLR / 256, DMODEL / 256), 512, 0, stream>>>(encb, gate_wb, h0b);
  gate_plug_kernel<<<BLR, 256, 0, stream>>>(h0b, encb, gate_b, bprobs, bucket, smoothed);

  // G2: down projection -> xb (bf16), occupancy-tiled
  gemm_t64<DO, DMODEL><<<dim3(BLR / 64, DO / 128), 256, 0, stream>>>(h0b, down_wb, xb);

  for (int k = 0; k < 3; ++k) {
    conv_kernel<<<BLR * 64 / 256, 256, 0, stream>>>(xb, rc_w + k * DO * 4, rc_b + k * DO, xconvb);
    gemm_ri<<<dim3(BLR / 32, DO / 128), 256, 0, stream>>>(
        xconvb, wrb + k * DO * DO, wib + k * DO * DO,
        wr_b + k * DO, wi_b + k * DO, e8 + k * DO, dsbuf);
    scan_p1<<<NB * NCH, 256, 0, stream>>>(dsbuf, ASsum);
    scan_p2<<<NB * NCH, 256, 0, stream>>>(dsbuf, ASsum, hsb);
    gemm_on<<<BLR / 32, 256, 0, stream>>>(hsb, owb + k * DO * DO, rn_w + k * DO, xb);
  }

  // up projection -> tmp2 (bf16), occupancy-tiled 64x128 (2048 blocks);
  // final rmsnorm -> out (f32)
  gemm_t64<DMODEL, DO><<<dim3(BLR / 64, DMODEL / 128), 256, 0, stream>>>(xb, up_wb, tmp2b);
  rmsnorm1024_kernel<<<BLR, 256, 0, stream>>>(tmp2b, norm_out_w, out);
}

// Round 10
// 458.104 us; speedup vs baseline: 1.0408x; 1.0408x over previous
//
#include <hip/hip_runtime.h>
#include <hip/hip_bf16.h>
#include <stdint.h>

typedef __attribute__((ext_vector_type(8))) short short8;   // 8 bf16 (4 VGPRs)
typedef __attribute__((ext_vector_type(4))) float f32x4;    // 4 fp32 acc
typedef __hip_bfloat16 bf16;

#define NB   8
#define LSEQ 2048
#define NM   256
#define DMODEL 1024
#define DO   256
#define BLR  16384   /* NB*LSEQ rows */
#define NCH  32      /* scan chunks (256 blocks; round-8 verified config) */
#define CLK  64      /* chunk length */
#define EMC  8       /* ema chunks */
#define EMCL 32      /* ema chunk length */

__device__ __forceinline__ float sigm(float x) { return 1.f / (1.f + __expf(-x)); }

__device__ __forceinline__ void gl_lds16(const void* g, void* l) {
  __builtin_amdgcn_global_load_lds((const __attribute__((address_space(1))) void*)g,
                                   (__attribute__((address_space(3))) void*)l, 16, 0, 0);
}

// inline-asm LDS read: invisible to compiler alias analysis (no auto vmcnt(0)
// drain vs in-flight global_load_lds). Fenced by lgkmcnt(0)+sched_barrier(0).
__device__ __forceinline__ short8 ds_read128(const bf16* p) {
  short8 r;
  unsigned a = (unsigned)(uintptr_t)(const __attribute__((address_space(3))) bf16*)p;
  asm volatile("ds_read_b128 %0, %1" : "=v"(r) : "v"(a));
  return r;
}

__device__ __forceinline__ unsigned short bf16bits(float v) {
  bf16 b = __float2bfloat16(v);
  return *(unsigned short*)&b;
}
__device__ __forceinline__ float bits2f(unsigned short u) {
  bf16 b = *(bf16*)&u;
  return __bfloat162float(b);
}

// ---------------- prep: enc cvt + all weight cvts + e8l2a in ONE dispatch ------
// ranges: [0, 4194304) float4 enc cvt; then weight chains; then e8.

__global__ __launch_bounds__(256) void prep_kernel(
    const float* __restrict__ encoder_out, ushort4* __restrict__ encb4,
    const float* __restrict__ gate_w, const float* __restrict__ down_w,
    const float* __restrict__ up_w, const float* __restrict__ wr_w,
    const float* __restrict__ wi_w, const float* __restrict__ ow_w,
    const float* __restrict__ log_a,
    bf16* __restrict__ gate_wb, bf16* __restrict__ down_wb, bf16* __restrict__ up_wb,
    bf16* __restrict__ wrb, bf16* __restrict__ wib, bf16* __restrict__ owb,
    float* __restrict__ e8) {
  int i = blockIdx.x * 256 + threadIdx.x;
  if (i < 4194304) {
    float4 v = ((const float4*)encoder_out)[i];
    ushort4 o;
    o.x = bf16bits(v.x); o.y = bf16bits(v.y); o.z = bf16bits(v.z); o.w = bf16bits(v.w);
    encb4[i] = o;
    return;
  }
  i -= 4194304;
  if (i < 1048576) { gate_wb[i] = __float2bfloat16(gate_w[i]); return; }
  i -= 1048576;
  if (i < 262144) { down_wb[i] = __float2bfloat16(down_w[i]); return; }
  i -= 262144;
  if (i < 262144) { up_wb[i] = __float2bfloat16(up_w[i]); return; }
  i -= 262144;
  if (i < 196608) { wrb[i] = __float2bfloat16(wr_w[i]); return; }
  i -= 196608;
  if (i < 196608) { wib[i] = __float2bfloat16(wi_w[i]); return; }
  i -= 196608;
  if (i < 196608) { owb[i] = __float2bfloat16(ow_w[i]); return; }
  i -= 196608;
  if (i < 768) {
    float ab = 1.f / (1.f + expf(-log_a[i]));
    e8[i] = 8.f * log2f(ab);
  }
}

// ---------------- EMA 2-pass (chunked scan over M=256) + bucket ----------------
// h_m = p_m*c_m + (1-p_m)*h_{m-1}. Chunk composition: h_out = A*h_in + S with
// A = prod(1-p), S = EMA-from-zero. p1: 256 ema blocks (b x cq x ch) + 64 bucket
// blocks. p2: 256 blocks, <=7-step prefix then store.

__global__ __launch_bounds__(256) void ema_p1(const float* __restrict__ cpt,
                                              const float* __restrict__ bprobs,
                                              const int* __restrict__ bidx,
                                              float2* __restrict__ ASe,
                                              int* __restrict__ bucket) {
  if (blockIdx.x < 256) {
    int blk = blockIdx.x;
    int b = blk >> 5, cq = (blk >> 3) & 3, ch = blk & 7;
    int c = cq * 256 + threadIdx.x;
    __shared__ float pl[EMCL];
    if (threadIdx.x < EMCL) {
      int m = ch * EMCL + threadIdx.x;
      pl[threadIdx.x] = bprobs[b * LSEQ + bidx[b * NM + m]];
    }
    __syncthreads();
    const float* cp = cpt + ((size_t)b * NM + ch * EMCL) * DMODEL + c;
    float A = 1.f, S = 0.f;
    for (int mm = 0; mm < EMCL; ++mm) {
      float pm = pl[mm];
      A *= (1.f - pm);
      S = pm * cp[(size_t)mm * DMODEL] + (1.f - pm) * S;
    }
    ASe[((size_t)(b * EMC + ch)) * DMODEL + c] = make_float2(A, S);
  } else {
    int i = (blockIdx.x - 256) * 256 + threadIdx.x;
    int b = i >> 11, l = i & 2047;
    const int* bi = bidx + b * NM;
    int lo = 0, hi = NM;
    while (lo < hi) {
      int mid = (lo + hi) >> 1;
      if (bi[mid] <= l) lo = mid + 1; else hi = mid;
    }
    int v = lo - 1;
    bucket[i] = v < 0 ? 0 : v;
  }
}

__global__ __launch_bounds__(256) void ema_p2(const float* __restrict__ cpt,
                                              const float* __restrict__ bprobs,
                                              const int* __restrict__ bidx,
                                              const float2* __restrict__ ASe,
                                              float* __restrict__ smoothed) {
  int blk = blockIdx.x;
  int b = blk >> 5, cq = (blk >> 3) & 3, ch = blk & 7;
  int c = cq * 256 + threadIdx.x;
  __shared__ float pl[EMCL];
  if (threadIdx.x < EMCL) {
    int m = ch * EMCL + threadIdx.x;
    pl[threadIdx.x] = bprobs[b * LSEQ + bidx[b * NM + m]];
  }
  __syncthreads();
  float h = 0.f;
  for (int j = 0; j < ch; ++j) {
    float2 as = ASe[((size_t)(b * EMC + j)) * DMODEL + c];
    h = __builtin_fmaf(as.x, h, as.y);
  }
  const float* cp = cpt + ((size_t)b * NM + ch * EMCL) * DMODEL + c;
  float* sp = smoothed + ((size_t)b * NM + ch * EMCL) * DMODEL + c;
  for (int mm = 0; mm < EMCL; ++mm) {
    float pm = pl[mm];
    h = pm * cp[(size_t)mm * DMODEL] + (1.f - pm) * h;
    sp[(size_t)mm * DMODEL] = h;
  }
}

// ---------------- gate + plugback elementwise (split from G1 epilogue) ----------
// h0 holds raw gemm logits (bf16); transformed IN PLACE:
// h0[m][n] = (1-p[m]) * sigm(h0[m][n] + gb[n]) * enc[m][n] + smoothed[b][bucket[m]][n]

__global__ __launch_bounds__(256) void gate_plug_kernel(bf16* __restrict__ h0,
                                                        const bf16* __restrict__ encb,
                                                        const float* __restrict__ gbias,
                                                        const float* __restrict__ bprobs,
                                                        const int* __restrict__ bucket,
                                                        const float* __restrict__ smoothed) {
  const int m = blockIdx.x;
  const int t = threadIdx.x;
  const int b = m >> 11;
  const float pm1 = 1.f - bprobs[m];
  const float* srow = smoothed + ((size_t)(b * NM + bucket[m])) * DMODEL + t * 4;
  const size_t base = (size_t)m * DMODEL + t * 4;
  ushort4 gr = *(const ushort4*)(h0 + base);
  ushort4 er = *(const ushort4*)(encb + base);
  float4 sm4 = *(const float4*)srow;
  float4 gb4 = *(const float4*)(gbias + t * 4);
  ushort4 o;
  o.x = bf16bits(pm1 * sigm(bits2f(gr.x) + gb4.x) * bits2f(er.x) + sm4.x);
  o.y = bf16bits(pm1 * sigm(bits2f(gr.y) + gb4.y) * bits2f(er.y) + sm4.y);
  o.z = bf16bits(pm1 * sigm(bits2f(gr.z) + gb4.z) * bits2f(er.z) + sm4.z);
  o.w = bf16bits(pm1 * sigm(bits2f(gr.w) + gb4.w) * bits2f(er.w) + sm4.w);
  *(ushort4*)(h0 + base) = o;
}

// ---------------- depthwise causal conv k=4, vectorized ushort4 ----------------
// thread handles 4 consecutive channels of one (b,l) row. grid = BLR*64/256.

__global__ __launch_bounds__(256) void conv_kernel(const bf16* __restrict__ x,
                                                   const float* __restrict__ cw,
                                                   const float* __restrict__ cb,
                                                   bf16* __restrict__ xcb) {
  int i4 = blockIdx.x * 256 + threadIdx.x;   // 4-channel group index
  int cg = i4 & 63;
  int bl = i4 >> 6;
  int l = bl & 2047;
  int c0 = cg << 2;
  float wf[4][4];
#pragma unroll
  for (int cc = 0; cc < 4; ++cc) {
    float4 w4 = ((const float4*)cw)[c0 + cc];
    wf[cc][0] = w4.x; wf[cc][1] = w4.y; wf[cc][2] = w4.z; wf[cc][3] = w4.w;
  }
  float4 cb4 = *(const float4*)(cb + c0);
  float s0 = cb4.x, s1 = cb4.y, s2 = cb4.z, s3 = cb4.w;
#pragma unroll
  for (int kk = 0; kk < 4; ++kk) {
    int ll = l - 3 + kk;
    if (ll >= 0) {
      ushort4 xv = *(const ushort4*)(x + (size_t)(bl + kk - 3) * DO + c0);
      s0 += wf[0][kk] * bits2f(xv.x);
      s1 += wf[1][kk] * bits2f(xv.y);
      s2 += wf[2][kk] * bits2f(xv.z);
      s3 += wf[3][kk] * bits2f(xv.w);
    }
  }
  ushort4 o;
  o.x = bf16bits(s0); o.y = bf16bits(s1); o.z = bf16bits(s2); o.w = bf16bits(s3);
  *(ushort4*)(xcb + (size_t)bl * DO + c0) = o;
}

// ---------------- chunked scan, 2 dispatches, 256 blocks each ----------------
// input packed uint: lo16 = d = 1-a (bf16), hi16 = s (bf16). h = (1-d)*h + s.

__global__ __launch_bounds__(256) void scan_p1(const unsigned int* __restrict__ ds,
                                               float2* __restrict__ AS) {
  int b = blockIdx.x / NCH, ch = blockIdx.x % NCH, c = threadIdx.x;
  size_t base = ((size_t)b * LSEQ + ch * CLK) * DO + c;
  float A = 1.f, S = 0.f;
  for (int t = 0; t < CLK; ++t) {
    unsigned int u = ds[base + (size_t)t * DO];
    float d = bits2f((unsigned short)(u & 0xffff));
    float s = bits2f((unsigned short)(u >> 16));
    float a = 1.f - d;
    A *= a;
    S = __builtin_fmaf(a, S, s);
  }
  AS[blockIdx.x * DO + c] = make_float2(A, S);
}

__global__ __launch_bounds__(256) void scan_p2(const unsigned int* __restrict__ ds,
                                               const float2* __restrict__ AS,
                                               bf16* __restrict__ hs) {
  int b = blockIdx.x / NCH, ch = blockIdx.x % NCH, c = threadIdx.x;
  // prefix over earlier chunks of this batch (L2-hot, <NCH iterations)
  float h = 0.f;
  for (int j = 0; j < ch; ++j) {
    float2 as = AS[(b * NCH + j) * DO + c];
    h = __builtin_fmaf(as.x, h, as.y);
  }
  size_t base = ((size_t)b * LSEQ + ch * CLK) * DO + c;
  for (int t = 0; t < CLK; ++t) {
    unsigned int u = ds[base + (size_t)t * DO];
    float d = bits2f((unsigned short)(u & 0xffff));
    float s = bits2f((unsigned short)(u >> 16));
    h = __builtin_fmaf(-d, h, h) + s;   // (1-d)*h + s
    hs[base + (size_t)t * DO] = __float2bfloat16(h);
  }
}

// ---------------- final rmsnorm over 1024, bf16 in -> f32 out ----------------

__global__ __launch_bounds__(256) void rmsnorm1024_kernel(const bf16* __restrict__ in,
                                                          const float* __restrict__ w,
                                                          float* __restrict__ out) {
  int row = blockIdx.x, t = threadIdx.x;
  ushort4 raw = ((const ushort4*)(in + (size_t)row * 1024))[t];
  float v0 = bits2f(raw.x), v1 = bits2f(raw.y), v2 = bits2f(raw.z), v3 = bits2f(raw.w);
  float ss = v0 * v0 + v1 * v1 + v2 * v2 + v3 * v3;
#pragma unroll
  for (int ofs = 32; ofs > 0; ofs >>= 1) ss += __shfl_down(ss, ofs, 64);
  __shared__ float wsum[4];
  if ((t & 63) == 0) wsum[t >> 6] = ss;
  __syncthreads();
  float tot = wsum[0] + wsum[1] + wsum[2] + wsum[3];
  float sc = rsqrtf(tot * (1.f / 1024.f) + 1e-6f);
  float4 wv = ((const float4*)w)[t];
  float4 o;
  o.x = v0 * sc * wv.x; o.y = v1 * sc * wv.y;
  o.z = v2 * sc * wv.z; o.w = v3 * sc * wv.w;
  ((float4*)(out + (size_t)row * 1024))[t] = o;
}

// ---------------- generic 64x128-tile 2-phase GEMM, occupancy-first ----------
// Used for down-proj (NC=256, KC=1024, grid 256x2) and up-proj (NC=1024,
// KC=256, grid 256x8 = 2048 blocks). LDS 24KB, acc 32 VGPR -> 4 blocks/CU.

template <int NC, int KC>
__global__ __launch_bounds__(256, 4) void gemm_t64(const bf16* __restrict__ A,
                                                   const bf16* __restrict__ W,
                                                   bf16* __restrict__ outb) {
  __shared__ __align__(16) bf16 As[64 * 64];    //  8 KB
  __shared__ __align__(16) bf16 Bs[128 * 64];   // 16 KB
  const int t = threadIdx.x;
  const int lane = t & 63;
  const int wv = t >> 6;
  const int wm = wv >> 1, wn = wv & 1;   // 2x2 waves, wave tile 32x64
  const int quad = lane >> 4, l16 = lane & 15;
  const int bm = blockIdx.x << 6, bn = blockIdx.y << 7;

  f32x4 acc[2][4] = {};

  for (int k0 = 0; k0 < KC; k0 += 64) {
    __syncthreads();
#pragma unroll
    for (int i = 0; i < 2; ++i) {   // A: 64 rows x 64 k
      int slot = i * 256 + t;
      int m = slot >> 3, lk8 = (slot & 7) ^ (m & 7);
      gl_lds16(A + (size_t)(bm + m) * KC + k0 + lk8 * 8, As + slot * 8);
    }
#pragma unroll
    for (int i = 0; i < 4; ++i) {   // B: 128 rows x 64 k
      int slot = i * 256 + t;
      int n = slot >> 3, lk8 = (slot & 7) ^ (n & 7);
      gl_lds16(W + (size_t)(bn + n) * KC + k0 + lk8 * 8, Bs + slot * 8);
    }
    __syncthreads();
#pragma unroll
    for (int ks = 0; ks < 2; ++ks) {
      short8 af[2], bfr[4];
#pragma unroll
      for (int i = 0; i < 2; ++i) {
        int m = wm * 32 + i * 16 + l16;
        int pa = (ks * 4 + quad) ^ (m & 7);
        af[i] = *(const short8*)(As + m * 64 + pa * 8);
      }
#pragma unroll
      for (int j = 0; j < 4; ++j) {
        int n = wn * 64 + j * 16 + l16;
        int pb = (ks * 4 + quad) ^ (n & 7);
        bfr[j] = *(const short8*)(Bs + n * 64 + pb * 8);
      }
#pragma unroll
      for (int i = 0; i < 2; ++i)
#pragma unroll
        for (int j = 0; j < 4; ++j)
          acc[i][j] = __builtin_amdgcn_mfma_f32_16x16x32_bf16(af[i], bfr[j], acc[i][j], 0, 0, 0);
    }
  }

#pragma unroll
  for (int i = 0; i < 2; ++i)
#pragma unroll
    for (int j = 0; j < 4; ++j)
#pragma unroll
      for (int r = 0; r < 4; ++r) {
        int m = bm + wm * 32 + i * 16 + quad * 4 + r;
        int n = bn + wn * 64 + j * 16 + l16;
        outb[(size_t)m * NC + n] = __float2bfloat16(acc[i][j][r]);
      }
}

// ---------------- 256x256 8-phase GEMM (T2+T3+T4+T5), N = DMODEL, pure ----------
// Used for G1 only (K=1024: 8 full pipeline iterations).

template <int KC>
__global__ __launch_bounds__(512, 2) void gemm256(const bf16* __restrict__ Ag,
                                                  const bf16* __restrict__ W,
                                                  bf16* __restrict__ outb) {
  __shared__ __align__(16) bf16 lds[2][4][128 * 64];   // [buf][A0,A1,B0,B1][...]
  const int t = threadIdx.x;
  const int lane = t & 63;
  const int wv = t >> 6;
  const int wm = wv >> 2, wn = wv & 3;
  const int quad = lane >> 4, l16 = lane & 15;
  const int bm = blockIdx.x << 8, bn = blockIdx.y << 8;
  constexpr int KT = KC >> 6;   // # 64-wide k-tiles (power of 2, >= 4)
  constexpr int KM = KT - 1;

  const int rr = t >> 3;                 // 0..63 staging row (q=0); q=1 adds +128 global
  const int cc = (t & 7) ^ (rr & 7);     // pre-swizzled source chunk

  f32x4 acc[8][4] = {};
  short8 af[4][2], bfr[2][2];

#define STAGE_A(BUF, H, KTI)                                                      \
  {                                                                               \
    int kk = ((KTI) & KM) << 6;                                                   \
    const bf16* s0 = Ag + (size_t)(bm + (H) * 64 + rr) * KC + kk + cc * 8;        \
    gl_lds16(s0, &lds[BUF][H][t * 8]);                                            \
    const bf16* s1 = Ag + (size_t)(bm + (H) * 64 + rr + 128) * KC + kk + cc * 8;  \
    gl_lds16(s1, &lds[BUF][H][(512 + t) * 8]);                                    \
  }
#define STAGE_B(BUF, H, KTI)                                                      \
  {                                                                               \
    int kk = ((KTI) & KM) << 6;                                                   \
    int n0 = (H) * 32 + (rr & 31) + ((rr >> 5) << 6);                             \
    const bf16* s0 = W + (size_t)(bn + n0) * KC + kk + cc * 8;                    \
    gl_lds16(s0, &lds[BUF][2 + (H)][t * 8]);                                      \
    const bf16* s1 = W + (size_t)(bn + n0 + 128) * KC + kk + cc * 8;              \
    gl_lds16(s1, &lds[BUF][2 + (H)][(512 + t) * 8]);                              \
  }
#define LD_A(BUF, MG)                                                             \
  _Pragma("unroll") for (int ii = 0; ii < 4; ++ii) {                              \
    int r = wm * 64 + ii * 16 + l16;                                              \
    _Pragma("unroll") for (int ks = 0; ks < 2; ++ks) {                            \
      int ch = (ks * 4 + quad) ^ (r & 7);                                         \
      af[ii][ks] = ds_read128(&lds[BUF][MG][(r * 8 + ch) * 8]);                   \
    }                                                                             \
  }
#define LD_B(BUF, NG)                                                             \
  _Pragma("unroll") for (int jj = 0; jj < 2; ++jj) {                              \
    int r = wn * 32 + jj * 16 + l16;                                              \
    _Pragma("unroll") for (int ks = 0; ks < 2; ++ks) {                            \
      int ch = (ks * 4 + quad) ^ (r & 7);                                         \
      bfr[jj][ks] = ds_read128(&lds[BUF][2 + (NG)][(r * 8 + ch) * 8]);            \
    }                                                                             \
  }
#define MMA(MG, NG)                                                               \
  _Pragma("unroll") for (int ks = 0; ks < 2; ++ks)                                \
  _Pragma("unroll") for (int ii = 0; ii < 4; ++ii)                                \
  _Pragma("unroll") for (int jj = 0; jj < 2; ++jj)                                \
    acc[(MG) * 4 + ii][(NG) * 2 + jj] = __builtin_amdgcn_mfma_f32_16x16x32_bf16(  \
        af[ii][ks], bfr[jj][ks], acc[(MG) * 4 + ii][(NG) * 2 + jj], 0, 0, 0);
#define BARR __builtin_amdgcn_s_barrier()
#define WAIT_LGKM asm volatile("s_waitcnt lgkmcnt(0)" ::: "memory")
#define WAIT_VM6 asm volatile("s_waitcnt vmcnt(6)" ::: "memory")
#define SBAR __builtin_amdgcn_sched_barrier(0)
#define PH(MG, NG)                   \
  BARR; WAIT_LGKM; SBAR;             \
  __builtin_amdgcn_s_setprio(1);     \
  MMA(MG, NG);                       \
  __builtin_amdgcn_s_setprio(0);     \
  SBAR;                              \
  BARR;
#define PH_V(MG, NG)                 \
  BARR; WAIT_LGKM; SBAR;             \
  __builtin_amdgcn_s_setprio(1);     \
  MMA(MG, NG);                       \
  __builtin_amdgcn_s_setprio(0);     \
  SBAR;                              \
  WAIT_VM6;                          \
  BARR;

  // prologue: buf0 <- kt0 complete; buf1 <- kt1 {A0, A1, B1} (B0 staged at g1)
  STAGE_A(0, 0, 0) STAGE_A(0, 1, 0) STAGE_B(0, 0, 0) STAGE_B(0, 1, 0)
  STAGE_A(1, 0, 1) STAGE_A(1, 1, 1) STAGE_B(1, 1, 1)
  WAIT_VM6;   // buf0's 8 loads (oldest) complete; buf1's 6 stay in flight
  BARR;

#pragma unroll 1
  for (int it = 0; it < (KT >> 1); ++it) {
    const int kt = it * 2;
    LD_A(0, 0) LD_B(0, 0)
    STAGE_B(1, 0, kt + 1)
    PH(0, 0)
    LD_B(0, 1)
    STAGE_A(0, 0, kt + 2)
    PH(0, 1)
    LD_A(0, 1)
    STAGE_B(0, 1, kt + 2)
    PH(1, 1)
    LD_B(0, 0)
    STAGE_A(0, 1, kt + 2)
    PH_V(1, 0)
    LD_A(1, 0) LD_B(1, 0)
    STAGE_B(0, 0, kt + 2)
    PH(0, 0)
    LD_B(1, 1)
    STAGE_A(1, 0, kt + 3)
    PH(0, 1)
    LD_A(1, 1)
    STAGE_B(1, 1, kt + 3)
    PH(1, 1)
    LD_B(1, 0)
    STAGE_A(1, 1, kt + 3)
    PH_V(1, 0)
  }

#undef STAGE_A
#undef STAGE_B
#undef LD_A
#undef LD_B
#undef MMA
#undef BARR
#undef WAIT_LGKM
#undef WAIT_VM6
#undef SBAR
#undef PH
#undef PH_V

#pragma unroll
  for (int i = 0; i < 8; ++i) {
#pragma unroll
    for (int j = 0; j < 4; ++j) {
#pragma unroll
      for (int r = 0; r < 4; ++r) {
        int m = bm + wm * 128 + i * 16 + quad * 4 + r;
        int n = bn + wn * 64 + j * 16 + l16;
        outb[(size_t)m * DMODEL + n] = __float2bfloat16(acc[i][j][r]);
      }
    }
  }
}

// ---------------- dual GEMM v2: occupancy-tiled 32x128, 1024 blocks ----------------

__global__ __launch_bounds__(256, 4) void gemm_ri(const bf16* __restrict__ A,
                                                  const bf16* __restrict__ Wr,
                                                  const bf16* __restrict__ Wi,
                                                  const float* __restrict__ rbias,
                                                  const float* __restrict__ ibias,
                                                  const float* __restrict__ e8,
                                                  unsigned int* __restrict__ ds_out) {
  __shared__ __align__(16) bf16 As[32 * 64];    //  4 KB
  __shared__ __align__(16) bf16 Br[128 * 64];   // 16 KB
  __shared__ __align__(16) bf16 Bi[128 * 64];   // 16 KB
  const int t = threadIdx.x;
  const int lane = t & 63;
  const int wv = t >> 6;
  const int wm = wv >> 1, wn = wv & 1;    // 2x2 waves, wave tile 16x64
  const int quad = lane >> 4, l16 = lane & 15;
  const int bm = blockIdx.x << 5;         // 32-row tile
  const int bn = blockIdx.y << 7;         // 128-col tile

  f32x4 ar[4] = {};
  f32x4 ai[4] = {};

  for (int k0 = 0; k0 < DO; k0 += 64) {
    __syncthreads();
    {  // A: 32 rows x 64 k, one 16B chunk per thread
      int m = t >> 3, lk8 = (t & 7) ^ (m & 7);
      gl_lds16(A + (size_t)(bm + m) * DO + k0 + lk8 * 8, As + t * 8);
    }
#pragma unroll
    for (int i = 0; i < 4; ++i) {  // Wr/Wi: 128 rows x 64 k each
      int slot = i * 256 + t;
      int n = slot >> 3, lk8 = (slot & 7) ^ (n & 7);
      gl_lds16(Wr + (size_t)(bn + n) * DO + k0 + lk8 * 8, Br + slot * 8);
      gl_lds16(Wi + (size_t)(bn + n) * DO + k0 + lk8 * 8, Bi + slot * 8);
    }
    __syncthreads();
#pragma unroll
    for (int ks = 0; ks < 2; ++ks) {
      int m = wm * 16 + l16;
      int pa = (ks * 4 + quad) ^ (m & 7);
      short8 af = *(const short8*)(As + m * 64 + pa * 8);
#pragma unroll
      for (int j = 0; j < 4; ++j) {
        int n = wn * 64 + j * 16 + l16;
        int pb = (ks * 4 + quad) ^ (n & 7);
        short8 br = *(const short8*)(Br + n * 64 + pb * 8);
        short8 bi = *(const short8*)(Bi + n * 64 + pb * 8);
        ar[j] = __builtin_amdgcn_mfma_f32_16x16x32_bf16(af, br, ar[j], 0, 0, 0);
        ai[j] = __builtin_amdgcn_mfma_f32_16x16x32_bf16(af, bi, ai[j], 0, 0, 0);
      }
    }
  }

#pragma unroll
  for (int j = 0; j < 4; ++j) {
    int n = bn + wn * 64 + j * 16 + l16;
    float rb = rbias[n], ib = ibias[n], e8n = e8[n];
#pragma unroll
    for (int r = 0; r < 4; ++r) {
      int m = bm + wm * 16 + quad * 4 + r;
      size_t idx = (size_t)m * DO + n;
      float rv = sigm(ar[j][r] + rb);
      float a = exp2f(rv * e8n);
      float d = 1.f - a;                               // ~5e-3, bf16-safe
      float iv = sigm(ai[j][r] + ib);
      float xc = __bfloat162float(A[idx]);             // xconv[m][n] == A[m][n]
      float s = sqrtf(fmaxf(1.f - a * a, 0.f)) * iv * xc;
      ds_out[idx] = (unsigned int)bf16bits(d) | ((unsigned int)bf16bits(s) << 16);
    }
  }
}

// ---------------- out-proj GEMM v2: 32x256 tiles + fused RMSNorm(256) -----------
// grid BLR/32 = 512 blocks, acc 32 VGPR, LDS 36.5KB.

__global__ __launch_bounds__(256, 4) void gemm_on(const bf16* __restrict__ A,   // hs [BLR,256]
                                                  const bf16* __restrict__ W,   // ow [256,256]
                                                  const float* __restrict__ rnw,
                                                  bf16* __restrict__ xb) {
  __shared__ __align__(16) bf16 As[32 * 64];    //  4 KB
  __shared__ __align__(16) bf16 Bs[256 * 64];   // 32 KB
  __shared__ float red[4][32];
  const int t = threadIdx.x;
  const int lane = t & 63;
  const int wn = t >> 6;           // wave = column slice of 64
  const int quad = lane >> 4, l16 = lane & 15;
  const int bm = blockIdx.x << 5;  // 32-row tile

  f32x4 acc[2][4] = {};

  for (int k0 = 0; k0 < DO; k0 += 64) {
    __syncthreads();
    {  // A: 32 rows x 64 k, one chunk per thread
      int m = t >> 3, lk8 = (t & 7) ^ (m & 7);
      gl_lds16(A + (size_t)(bm + m) * DO + k0 + lk8 * 8, As + t * 8);
    }
#pragma unroll
    for (int i = 0; i < 8; ++i) {  // B: 256 rows x 64 k
      int slot = i * 256 + t;
      int n = slot >> 3, lk8 = (slot & 7) ^ (n & 7);
      gl_lds16(W + (size_t)n * DO + k0 + lk8 * 8, Bs + slot * 8);
    }
    __syncthreads();
#pragma unroll
    for (int ks = 0; ks < 2; ++ks) {
      short8 af[2], bfr[4];
#pragma unroll
      for (int i = 0; i < 2; ++i) {
        int m = i * 16 + l16;
        int pa = (ks * 4 + quad) ^ (m & 7);
        af[i] = *(const short8*)(As + m * 64 + pa * 8);
      }
#pragma unroll
      for (int j = 0; j < 4; ++j) {
        int n = wn * 64 + j * 16 + l16;
        int pb = (ks * 4 + quad) ^ (n & 7);
        bfr[j] = *(const short8*)(Bs + n * 64 + pb * 8);
      }
#pragma unroll
      for (int i = 0; i < 2; ++i)
#pragma unroll
        for (int j = 0; j < 4; ++j)
          acc[i][j] = __builtin_amdgcn_mfma_f32_16x16x32_bf16(af[i], bfr[j], acc[i][j], 0, 0, 0);
    }
  }

  float part[2][4];
#pragma unroll
  for (int i = 0; i < 2; ++i)
#pragma unroll
    for (int r = 0; r < 4; ++r) {
      float s = 0.f;
#pragma unroll
      for (int j = 0; j < 4; ++j) s += acc[i][j][r] * acc[i][j][r];
      part[i][r] = s;
    }
#pragma unroll
  for (int mask = 1; mask <= 8; mask <<= 1)
#pragma unroll
    for (int i = 0; i < 2; ++i)
#pragma unroll
      for (int r = 0; r < 4; ++r) part[i][r] += __shfl_xor(part[i][r], mask, 64);
  if (l16 == 0) {
#pragma unroll
    for (int i = 0; i < 2; ++i)
#pragma unroll
      for (int r = 0; r < 4; ++r) red[wn][i * 16 + quad * 4 + r] = part[i][r];
  }
  __syncthreads();
#pragma unroll
  for (int i = 0; i < 2; ++i) {
#pragma unroll
    for (int r = 0; r < 4; ++r) {
      int ml = i * 16 + quad * 4 + r;
      float tot = red[0][ml] + red[1][ml] + red[2][ml] + red[3][ml];
      float sc = rsqrtf(tot * (1.f / 256.f) + 1e-6f);
#pragma unroll
      for (int j = 0; j < 4; ++j) {
        int n = wn * 64 + j * 16 + l16;
        xb[(size_t)(bm + ml) * DO + n] = __float2bfloat16(acc[i][j][r] * sc * rnw[n]);
      }
    }
  }
}

// ---------------- launch ----------------

extern "C" void kernel_launch(void* const* d_in, const int* in_sizes, int n_in,
                              void* d_out, int out_size, void* d_ws, size_t ws_size,
                              hipStream_t stream) {
  const float* concept_out = (const float*)d_in[0];
  const float* encoder_out = (const float*)d_in[1];
  const float* bprobs      = (const float*)d_in[2];
  const int*   bidx        = (const int*)d_in[3];
  const float* gate_w      = (const float*)d_in[4];
  const float* gate_b      = (const float*)d_in[5];
  const float* down_w      = (const float*)d_in[6];
  const float* up_w        = (const float*)d_in[7];
  const float* norm_out_w  = (const float*)d_in[8];
  const float* rc_w        = (const float*)d_in[9];
  const float* rc_b        = (const float*)d_in[10];
  const float* wr_w        = (const float*)d_in[11];
  const float* wr_b        = (const float*)d_in[12];
  const float* wi_w        = (const float*)d_in[13];
  const float* wi_b        = (const float*)d_in[14];
  const float* log_a       = (const float*)d_in[15];
  const float* ow_w        = (const float*)d_in[16];
  const float* rn_w        = (const float*)d_in[17];
  float* out = (float*)d_out;
  (void)in_sizes; (void)n_in; (void)out_size; (void)ws_size;

  char* base = (char*)d_ws;
  size_t off = 0;
  auto alloc = [&](size_t bytes) -> char* {
    char* p = base + off;
    off += (bytes + 255) & ~(size_t)255;
    return p;
  };
  float* smoothed = (float*)alloc((size_t)NB * NM * DMODEL * 4);   // 8 MB
  int*   bucket   = (int*)alloc((size_t)BLR * 4);
  bf16*  gate_wb  = (bf16*)alloc((size_t)DMODEL * DMODEL * 2);
  bf16*  down_wb  = (bf16*)alloc((size_t)DO * DMODEL * 2);
  bf16*  up_wb    = (bf16*)alloc((size_t)DMODEL * DO * 2);
  bf16*  wrb      = (bf16*)alloc((size_t)3 * DO * DO * 2);
  bf16*  wib      = (bf16*)alloc((size_t)3 * DO * DO * 2);
  bf16*  owb      = (bf16*)alloc((size_t)3 * DO * DO * 2);
  float* e8       = (float*)alloc(3 * DO * 4);
  float2* ASsum   = (float2*)alloc((size_t)NB * NCH * DO * 8);     // 512 KB scan summaries
  float2* ASe     = (float2*)alloc((size_t)NB * EMC * DMODEL * 8); // 512 KB ema summaries
  bf16*  xb       = (bf16*)alloc((size_t)BLR * DO * 2);            // 8 MB layer io

  // reused overlay region — offsets computed from actual buffer sizes
  const size_t SZ_ENC   = (size_t)BLR * DMODEL * 2;   // 32 MB
  const size_t SZ_XCONV = (size_t)BLR * DO * 2;       //  8 MB
  const size_t SZ_DS    = (size_t)BLR * DO * 4;       // 16 MB (packed uint32!)
  char* RA = alloc(2 * SZ_ENC);                       // 64 MB
  // head overlays
  bf16*  encb = (bf16*)RA;
  bf16*  h0b  = (bf16*)(RA + SZ_ENC);   // raw G1 logits, then gated in-place
  // layer overlays (xconvb | dsbuf | hsb disjoint: 8 + 16 + 8 = 32 MB)
  bf16*         xconvb = (bf16*)RA;
  unsigned int* dsbuf  = (unsigned int*)(RA + SZ_XCONV);
  bf16*         hsb    = (bf16*)(RA + SZ_XCONV + SZ_DS);
  // tail overlay
  bf16*  tmp2b  = (bf16*)RA;

  // prep: enc cvt (4194304 vec4) + weight cvts (2162688) + e8 (768)
  prep_kernel<<<(4194304 + 2163456 + 255) / 256, 256, 0, stream>>>(
      encoder_out, (ushort4*)encb,
      gate_w, down_w, up_w, wr_w, wi_w, ow_w, log_a,
      gate_wb, down_wb, up_wb, wrb, wib, owb, e8);
  // ema 2-pass (256 ema blocks + 64 bucket blocks; then 256 prefix blocks)
  ema_p1<<<256 + BLR / 256, 256, 0, stream>>>(concept_out, bprobs, bidx, ASe, bucket);
  ema_p2<<<256, 256, 0, stream>>>(concept_out, bprobs, bidx, ASe, smoothed);

  // G1: pure gate GEMM -> h0b (raw logits), then fused gate+plugback in place
  gemm256<DMODEL><<<dim3(BLR / 256, DMODEL / 256), 512, 0, stream>>>(encb, gate_wb, h0b);
  gate_plug_kernel<<<BLR, 256, 0, stream>>>(h0b, encb, gate_b, bprobs, bucket, smoothed);

  // G2: down projection -> xb (bf16), occupancy-tiled
  gemm_t64<DO, DMODEL><<<dim3(BLR / 64, DO / 128), 256, 0, stream>>>(h0b, down_wb, xb);

  for (int k = 0; k < 3; ++k) {
    conv_kernel<<<BLR * 64 / 256, 256, 0, stream>>>(xb, rc_w + k * DO * 4, rc_b + k * DO, xconvb);
    gemm_ri<<<dim3(BLR / 32, DO / 128), 256, 0, stream>>>(
        xconvb, wrb + k * DO * DO, wib + k * DO * DO,
        wr_b + k * DO, wi_b + k * DO, e8 + k * DO, dsbuf);
    scan_p1<<<NB * NCH, 256, 0, stream>>>(dsbuf, ASsum);
    scan_p2<<<NB * NCH, 256, 0, stream>>>(dsbuf, ASsum, hsb);
    gemm_on<<<BLR / 32, 256, 0, stream>>>(hsb, owb + k * DO * DO, rn_w + k * DO, xb);
  }

  // up projection -> tmp2 (bf16), occupancy-tiled 64x128 (2048 blocks);
  // final rmsnorm -> out (f32)
  gemm_t64<DMODEL, DO><<<dim3(BLR / 64, DMODEL / 128), 256, 0, stream>>>(xb, up_wb, tmp2b);
  rmsnorm1024_kernel<<<BLR, 256, 0, stream>>>(tmp2b, norm_out_w, out);
}